// Round 6
// baseline (108.462 us; speedup 1.0000x reference)
//
#include <hip/hip_runtime.h>

typedef float f32x4 __attribute__((ext_vector_type(4)));
typedef short short8 __attribute__((ext_vector_type(8)));

#define NTYPES 4

// ws layout (bytes):
//   [0,64)        meta ints: 0-3 counts, 4-7 cursors, 8-12 bases (bases[i]=meta[8+i])
//   [512,1024)    dump row (pad-node store sink)
//   [1024,...)    perm[ntiles*64] ints (pad slots = -1)
//   [402432,)     W1T bf16 [4][256][128]  W1T[t][hcol][k]
//   [664576,)     W2T bf16 [4][128][256]  W2T[t][ocol][h]

static __device__ __forceinline__ unsigned short f2bf(float f) {
  union { float f; unsigned int u; } v; v.f = f;
  unsigned int u = v.u;
  unsigned int r = u + 0x7FFFu + ((u >> 16) & 1u);   // round-nearest-even
  return (unsigned short)(r >> 16);
}

#define LGKM_BAR() do { \
  asm volatile("s_waitcnt lgkmcnt(0)" ::: "memory"); \
  __builtin_amdgcn_s_barrier(); \
  __builtin_amdgcn_sched_barrier(0); } while (0)

// weight transpose+cast; block 0 also zeroes meta (replaces hipMemsetAsync node)
__global__ __launch_bounds__(256) void k_prep(const float* __restrict__ W1,
                                              const float* __restrict__ W2,
                                              unsigned short* __restrict__ W1T,
                                              unsigned short* __restrict__ W2T,
                                              int* __restrict__ meta) {
  if (blockIdx.x == 0 && threadIdx.x < 16) meta[threadIdx.x] = 0;
  int i = blockIdx.x * 256 + threadIdx.x;   // 0..131071
  int t = i >> 15, rem = i & 32767;
  {
    int c = rem >> 7, k = rem & 127;        // W1T[t][c][k] = W1[t][k][c]
    W1T[i] = f2bf(W1[(t << 15) + k * 256 + c]);
  }
  {
    int o = rem >> 8, h = rem & 255;        // W2T[t][o][h] = W2[t][h][o]
    W2T[i] = f2bf(W2[(t << 15) + h * 128 + o]);
  }
}

__global__ __launch_bounds__(256) void k_hist(const int* __restrict__ NT, int n,
                                              int* __restrict__ meta) {
  __shared__ int c[NTYPES];
  if (threadIdx.x < NTYPES) c[threadIdx.x] = 0;
  __syncthreads();
  int i = blockIdx.x * 256 + threadIdx.x;
  if (i < n) atomicAdd(&c[NT[i]], 1);
  __syncthreads();
  if (threadIdx.x < NTYPES && c[threadIdx.x] > 0)
    atomicAdd(&meta[threadIdx.x], c[threadIdx.x]);
}

// scatter + inline prefix (from final counts) + base publish + pad fill
__global__ __launch_bounds__(256) void k_scatter(const int* __restrict__ NT, int n,
                                                 int* __restrict__ meta,
                                                 int* __restrict__ perm) {
  __shared__ int cnt[NTYPES];
  __shared__ int cbase[NTYPES];
  __shared__ int sb[NTYPES + 1];
  if (threadIdx.x < NTYPES) cnt[threadIdx.x] = 0;
  if (threadIdx.x == 0) {
    int b = 0; sb[0] = 0;
    for (int t = 0; t < NTYPES; ++t) {
      b += (meta[t] + 63) & ~63;           // pad each segment to 64
      sb[t + 1] = b;
    }
  }
  __syncthreads();
  int i = blockIdx.x * 256 + threadIdx.x;
  int t = 0, r = 0;
  bool valid = (i < n);
  if (valid) { t = NT[i]; r = atomicAdd(&cnt[t], 1); }
  __syncthreads();
  if (threadIdx.x < NTYPES)
    cbase[threadIdx.x] = atomicAdd(&meta[4 + threadIdx.x], cnt[threadIdx.x]);
  __syncthreads();
  if (valid) perm[sb[t] + cbase[t] + r] = i;
  if (blockIdx.x == 0) {
    if (threadIdx.x <= NTYPES) meta[8 + threadIdx.x] = sb[threadIdx.x];
    int tt = threadIdx.x >> 6, j = threadIdx.x & 63;   // pad count per type <= 63
    int p = sb[tt] + meta[tt] + j;
    if (p < sb[tt + 1]) perm[p] = -1;
  }
}

// Weights-stationary persistent MLP with inline X gather.
// Grid = 512 blocks, 128 blocks/type; block handles tiles lb, lb+128, ... of
// its type. W1/W2 fragment slices in registers across the whole tile loop.
// Per tile: gather X rows to regs (f32) -> cvt bf16 -> swizzled LDS ->
// layer1 -> h(LDS) -> layer2 -> out transpose via LDS -> row-coalesced store.
__global__ __launch_bounds__(512, 4) void k_mlpw(
    const float* __restrict__ X, const int* __restrict__ perm,
    const int* __restrict__ meta,
    const unsigned short* __restrict__ W1T, const unsigned short* __restrict__ W2T,
    const float* __restrict__ B1, const float* __restrict__ B2,
    float* __restrict__ OUT, float* __restrict__ dump) {
  __shared__ __align__(16) unsigned char x_lds[16384];   // x tile bf16 (swizzled)
  __shared__ __align__(16) unsigned char h_lds[32768];   // h bf16; reused as out f32

  const int tid = threadIdx.x;
  const int l  = tid & 63, w = tid >> 6;   // wave 0..7
  const int lo = l & 15,  hi = l >> 4;

  const int t  = blockIdx.x >> 7;          // 128 blocks per type
  const int lb = blockIdx.x & 127;
  const int g0 = meta[8 + t] >> 6;         // first tile of this type
  const int g1 = meta[9 + t] >> 6;         // one past last
  const int nt = g1 - g0 - lb;
  if (nt <= 0) return;
  const int cnt = (nt + 127) >> 7;

  // ---- weights + biases into registers, once per block ----
  const unsigned short* w1t = W1T + (t << 15);
  const unsigned short* w2t = W2T + (t << 15);
  short8 a1[4][2], a2[8];
  #pragma unroll
  for (int ks = 0; ks < 4; ++ks)
    #pragma unroll
    for (int m = 0; m < 2; ++m)
      a1[ks][m] = *(const short8*)(w1t + (w * 32 + m * 16 + lo) * 128 + ks * 32 + hi * 8);
  #pragma unroll
  for (int ks = 0; ks < 8; ++ks)
    a2[ks] = *(const short8*)(w2t + (w * 16 + lo) * 256 + ks * 32 + hi * 8);
  f32x4 bb1[2], bb2;
  #pragma unroll
  for (int m = 0; m < 2; ++m)
    bb1[m] = *(const f32x4*)(B1 + t * 256 + w * 32 + m * 16 + hi * 4);
  bb2 = *(const f32x4*)(B2 + t * 128 + w * 16 + hi * 4);

  const int gr  = tid >> 3;          // gather row 0..63
  const int gq  = tid & 7;           // 16-float column group

  for (int j = 0; j < cnt; ++j) {
    const int g = g0 + lb + j * 128;

    // ---- gather one row-sixteenth to regs, cvt, swizzled LDS write ----
    {
      int ridg = perm[g * 64 + gr];
      float4 v0 = make_float4(0.f, 0.f, 0.f, 0.f), v1 = v0, v2 = v0, v3 = v0;
      if (ridg >= 0) {
        const float4* src = (const float4*)(X + (size_t)ridg * 128 + gq * 16);
        v0 = src[0]; v1 = src[1]; v2 = src[2]; v3 = src[3];
      }
      short8 c0, c1;
      c0[0] = (short)f2bf(v0.x); c0[1] = (short)f2bf(v0.y);
      c0[2] = (short)f2bf(v0.z); c0[3] = (short)f2bf(v0.w);
      c0[4] = (short)f2bf(v1.x); c0[5] = (short)f2bf(v1.y);
      c0[6] = (short)f2bf(v1.z); c0[7] = (short)f2bf(v1.w);
      c1[0] = (short)f2bf(v2.x); c1[1] = (short)f2bf(v2.y);
      c1[2] = (short)f2bf(v2.z); c1[3] = (short)f2bf(v2.w);
      c1[4] = (short)f2bf(v3.x); c1[5] = (short)f2bf(v3.y);
      c1[6] = (short)f2bf(v3.z); c1[7] = (short)f2bf(v3.w);
      const int base = gr * 256 + gq * 32;
      const int swz = (gr & 7) << 4;
      *(short8*)(x_lds + (base ^ swz)) = c0;
      *(short8*)(x_lds + ((base + 16) ^ swz)) = c1;
    }
    LGKM_BAR();   // x tile visible

    // ---- layer 1: W1 frags in regs (A), x from LDS (B) ----
    f32x4 acc[2][4];
    #pragma unroll
    for (int m = 0; m < 2; ++m)
      #pragma unroll
      for (int n = 0; n < 4; ++n) acc[m][n] = (f32x4){0.f, 0.f, 0.f, 0.f};
    #pragma unroll
    for (int ks = 0; ks < 4; ++ks) {
      const int k8 = ks * 32 + hi * 8;
      short8 b[4];
      #pragma unroll
      for (int n = 0; n < 4; ++n) {
        int row = n * 16 + lo;
        int byte = (row * 256 + k8 * 2) ^ ((row & 7) << 4);
        b[n] = *(const short8*)(x_lds + byte);
      }
      #pragma unroll
      for (int m = 0; m < 2; ++m)
        #pragma unroll
        for (int n = 0; n < 4; ++n)
          acc[m][n] = __builtin_amdgcn_mfma_f32_16x16x32_bf16(a1[ks][m], b[n], acc[m][n], 0, 0, 0);
    }

    // bias + relu -> h LDS (lane owns 4 consecutive hcols -> b64 writes)
    #pragma unroll
    for (int m = 0; m < 2; ++m) {
      const int hc = w * 32 + m * 16 + hi * 4;
      #pragma unroll
      for (int n = 0; n < 4; ++n) {
        int row = n * 16 + lo;
        ushort4 hv;
        hv.x = f2bf(fmaxf(acc[m][n][0] + bb1[m][0], 0.f));
        hv.y = f2bf(fmaxf(acc[m][n][1] + bb1[m][1], 0.f));
        hv.z = f2bf(fmaxf(acc[m][n][2] + bb1[m][2], 0.f));
        hv.w = f2bf(fmaxf(acc[m][n][3] + bb1[m][3], 0.f));
        int byte = (row * 512 + hc * 2) ^ ((row & 7) << 4);
        *(ushort4*)(h_lds + byte) = hv;
      }
    }
    LGKM_BAR();   // h visible; x_lds reads done

    // ---- layer 2: W2 frags in regs (A), h from LDS (B) ----
    f32x4 acc2[4];
    #pragma unroll
    for (int n = 0; n < 4; ++n) acc2[n] = (f32x4){0.f, 0.f, 0.f, 0.f};
    #pragma unroll
    for (int ks = 0; ks < 8; ++ks) {
      const int k8 = ks * 32 + hi * 8;
      short8 b[4];
      #pragma unroll
      for (int n = 0; n < 4; ++n) {
        int row = n * 16 + lo;
        int byte = (row * 512 + k8 * 2) ^ ((row & 7) << 4);
        b[n] = *(const short8*)(h_lds + byte);
      }
      #pragma unroll
      for (int n = 0; n < 4; ++n)
        acc2[n] = __builtin_amdgcn_mfma_f32_16x16x32_bf16(a2[ks], b[n], acc2[n], 0, 0, 0);
    }

    // rowids for the store phase (4 per thread)
    int rid[4];
    #pragma unroll
    for (int p = 0; p < 4; ++p) rid[p] = perm[g * 64 + p * 16 + (tid >> 5)];

    LGKM_BAR();   // all h reads done -> safe to overwrite h_lds with out f32

    // out f32 -> LDS (lane owns 4 consecutive ocols, swizzled rows)
    #pragma unroll
    for (int n = 0; n < 4; ++n) {
      int row = n * 16 + lo;
      const int oc = w * 16 + hi * 4;
      f32x4 o = acc2[n];
      o[0] += bb2[0]; o[1] += bb2[1]; o[2] += bb2[2]; o[3] += bb2[3];
      int byte = (row * 512 + oc * 4) ^ ((row & 7) << 4);
      *(f32x4*)(h_lds + byte) = o;
    }
    LGKM_BAR();   // out tile visible

    // row-coalesced scatter: 32 consecutive lanes write one contiguous 512B row
    #pragma unroll
    for (int p = 0; p < 4; ++p) {
      int off = p * 8192 + tid * 16;
      int row = off >> 9;
      f32x4 v = *(const f32x4*)(h_lds + (off ^ ((row & 7) << 4)));
      int colf = (off & 511) >> 2;
      float* dst = (rid[p] >= 0) ? (OUT + (size_t)rid[p] * 128 + colf) : (dump + colf);
      *(f32x4*)dst = v;
    }
    // global stores overlap next tile's gather (no vmcnt drain in LGKM_BAR)
  }
}

extern "C" void kernel_launch(void* const* d_in, const int* in_sizes, int n_in,
                              void* d_out, int out_size, void* d_ws, size_t ws_size,
                              hipStream_t stream) {
  const float* X  = (const float*)d_in[0];
  const int*   NT = (const int*)d_in[1];
  const float* W1 = (const float*)d_in[2];
  const float* B1 = (const float*)d_in[3];
  const float* W2 = (const float*)d_in[4];
  const float* B2 = (const float*)d_in[5];
  float* OUT = (float*)d_out;
  const int n = in_sizes[1];

  char* ws = (char*)d_ws;
  int* meta = (int*)ws;                                   // counts/cursors/bases
  float* dump = (float*)(ws + 512);
  int* perm = (int*)(ws + 1024);
  unsigned short* W1T = (unsigned short*)(ws + 402432);
  unsigned short* W2T = (unsigned short*)(ws + 664576);

  k_prep<<<512, 256, 0, stream>>>(W1, W2, W1T, W2T, meta);
  const int nb = (n + 255) / 256;
  k_hist<<<nb, 256, 0, stream>>>(NT, n, meta);
  k_scatter<<<nb, 256, 0, stream>>>(NT, n, meta, perm);
  k_mlpw<<<512, 512, 0, stream>>>(X, perm, meta, W1T, W2T, B1, B2, OUT, dump);
}

// Round 7
// 63.969 us; speedup vs baseline: 1.6955x; 1.6955x over previous
//
#include <hip/hip_runtime.h>

typedef float f32x4 __attribute__((ext_vector_type(4)));
typedef short short8 __attribute__((ext_vector_type(8)));

#define NTYPES 4

// ws layout (bytes):
//   [0,64)        meta ints: 0-3 counts, 4-7 cursors, 8-12 bases (bases[i]=meta[8+i])
//   [512,1024)    dump row (pad-node store sink)
//   [1024,...)    perm[ntiles*64] ints (pad slots = -1)
//   [402432,)     W1T bf16 [4][256][128]  W1T[t][hcol][k]
//   [664576,)     W2T bf16 [4][128][256]  W2T[t][ocol][h]

static __device__ __forceinline__ unsigned short f2bf(float f) {
  union { float f; unsigned int u; } v; v.f = f;
  unsigned int u = v.u;
  unsigned int r = u + 0x7FFFu + ((u >> 16) & 1u);   // round-nearest-even
  return (unsigned short)(r >> 16);
}

#define LGKM_BAR() do { \
  asm volatile("s_waitcnt lgkmcnt(0)" ::: "memory"); \
  __builtin_amdgcn_s_barrier(); \
  __builtin_amdgcn_sched_barrier(0); } while (0)

// weight transpose+cast; block 0 also zeroes meta (replaces hipMemsetAsync node)
__global__ __launch_bounds__(256) void k_prep(const float* __restrict__ W1,
                                              const float* __restrict__ W2,
                                              unsigned short* __restrict__ W1T,
                                              unsigned short* __restrict__ W2T,
                                              int* __restrict__ meta) {
  if (blockIdx.x == 0 && threadIdx.x < 16) meta[threadIdx.x] = 0;
  int i = blockIdx.x * 256 + threadIdx.x;   // 0..131071
  int t = i >> 15, rem = i & 32767;
  {
    int c = rem >> 7, k = rem & 127;        // W1T[t][c][k] = W1[t][k][c]
    W1T[i] = f2bf(W1[(t << 15) + k * 256 + c]);
  }
  {
    int o = rem >> 8, h = rem & 255;        // W2T[t][o][h] = W2[t][h][o]
    W2T[i] = f2bf(W2[(t << 15) + h * 128 + o]);
  }
}

__global__ __launch_bounds__(256) void k_hist(const int* __restrict__ NT, int n,
                                              int* __restrict__ meta) {
  __shared__ int c[NTYPES];
  if (threadIdx.x < NTYPES) c[threadIdx.x] = 0;
  __syncthreads();
  int i = blockIdx.x * 256 + threadIdx.x;
  if (i < n) atomicAdd(&c[NT[i]], 1);
  __syncthreads();
  if (threadIdx.x < NTYPES && c[threadIdx.x] > 0)
    atomicAdd(&meta[threadIdx.x], c[threadIdx.x]);
}

// scatter + inline prefix (from final counts) + base publish + pad fill
__global__ __launch_bounds__(256) void k_scatter(const int* __restrict__ NT, int n,
                                                 int* __restrict__ meta,
                                                 int* __restrict__ perm) {
  __shared__ int cnt[NTYPES];
  __shared__ int cbase[NTYPES];
  __shared__ int sb[NTYPES + 1];
  if (threadIdx.x < NTYPES) cnt[threadIdx.x] = 0;
  if (threadIdx.x == 0) {
    int b = 0; sb[0] = 0;
    for (int t = 0; t < NTYPES; ++t) {
      b += (meta[t] + 63) & ~63;           // pad each segment to 64
      sb[t + 1] = b;
    }
  }
  __syncthreads();
  int i = blockIdx.x * 256 + threadIdx.x;
  int t = 0, r = 0;
  bool valid = (i < n);
  if (valid) { t = NT[i]; r = atomicAdd(&cnt[t], 1); }
  __syncthreads();
  if (threadIdx.x < NTYPES)
    cbase[threadIdx.x] = atomicAdd(&meta[4 + threadIdx.x], cnt[threadIdx.x]);
  __syncthreads();
  if (valid) perm[sb[t] + cbase[t] + r] = i;
  if (blockIdx.x == 0) {
    if (threadIdx.x <= NTYPES) meta[8 + threadIdx.x] = sb[threadIdx.x];
    int tt = threadIdx.x >> 6, j = threadIdx.x & 63;   // pad count per type <= 63
    int p = sb[tt] + meta[tt] + j;
    if (p < sb[tt + 1]) perm[p] = -1;
  }
}

// Weights-stationary persistent MLP with inline X gather.
// Grid = 512 blocks, 128 blocks/type; block handles tiles lb, lb+128, ... of
// its type. W1/W2 fragment slices in registers across the whole tile loop.
// __launch_bounds__(512, 2): VGPR cap 256 — REQUIRED. (512,4) made the
// allocator pick 64 VGPRs and spill the 64-VGPR weight-fragment set to
// scratch: +100MB FETCH / +83MB WRITE, 105us (round-6 regression).
__global__ __launch_bounds__(512, 2) void k_mlpw(
    const float* __restrict__ X, const int* __restrict__ perm,
    const int* __restrict__ meta,
    const unsigned short* __restrict__ W1T, const unsigned short* __restrict__ W2T,
    const float* __restrict__ B1, const float* __restrict__ B2,
    float* __restrict__ OUT, float* __restrict__ dump) {
  __shared__ __align__(16) unsigned char x_lds[16384];   // x tile bf16 (swizzled)
  __shared__ __align__(16) unsigned char h_lds[32768];   // h bf16; reused as out f32

  const int tid = threadIdx.x;
  const int l  = tid & 63, w = tid >> 6;   // wave 0..7
  const int lo = l & 15,  hi = l >> 4;

  const int t  = blockIdx.x >> 7;          // 128 blocks per type
  const int lb = blockIdx.x & 127;
  const int g0 = meta[8 + t] >> 6;         // first tile of this type
  const int g1 = meta[9 + t] >> 6;         // one past last
  const int nt = g1 - g0 - lb;
  if (nt <= 0) return;
  const int cnt = (nt + 127) >> 7;

  // ---- weights + biases into registers, once per block ----
  const unsigned short* w1t = W1T + (t << 15);
  const unsigned short* w2t = W2T + (t << 15);
  short8 a1[4][2], a2[8];
  #pragma unroll
  for (int ks = 0; ks < 4; ++ks)
    #pragma unroll
    for (int m = 0; m < 2; ++m)
      a1[ks][m] = *(const short8*)(w1t + (w * 32 + m * 16 + lo) * 128 + ks * 32 + hi * 8);
  #pragma unroll
  for (int ks = 0; ks < 8; ++ks)
    a2[ks] = *(const short8*)(w2t + (w * 16 + lo) * 256 + ks * 32 + hi * 8);
  f32x4 bb1[2], bb2;
  #pragma unroll
  for (int m = 0; m < 2; ++m)
    bb1[m] = *(const f32x4*)(B1 + t * 256 + w * 32 + m * 16 + hi * 4);
  bb2 = *(const f32x4*)(B2 + t * 128 + w * 16 + hi * 4);

  const int gr  = tid >> 3;          // gather row 0..63
  const int gq  = tid & 7;           // 16-float column group

  for (int j = 0; j < cnt; ++j) {
    const int g = g0 + lb + j * 128;

    // ---- gather one row-eighth to regs, cvt, swizzled LDS write ----
    {
      int ridg = perm[g * 64 + gr];
      float4 v0 = make_float4(0.f, 0.f, 0.f, 0.f), v1 = v0, v2 = v0, v3 = v0;
      if (ridg >= 0) {
        const float4* src = (const float4*)(X + (size_t)ridg * 128 + gq * 16);
        v0 = src[0]; v1 = src[1]; v2 = src[2]; v3 = src[3];
      }
      short8 c0, c1;
      c0[0] = (short)f2bf(v0.x); c0[1] = (short)f2bf(v0.y);
      c0[2] = (short)f2bf(v0.z); c0[3] = (short)f2bf(v0.w);
      c0[4] = (short)f2bf(v1.x); c0[5] = (short)f2bf(v1.y);
      c0[6] = (short)f2bf(v1.z); c0[7] = (short)f2bf(v1.w);
      c1[0] = (short)f2bf(v2.x); c1[1] = (short)f2bf(v2.y);
      c1[2] = (short)f2bf(v2.z); c1[3] = (short)f2bf(v2.w);
      c1[4] = (short)f2bf(v3.x); c1[5] = (short)f2bf(v3.y);
      c1[6] = (short)f2bf(v3.z); c1[7] = (short)f2bf(v3.w);
      const int base = gr * 256 + gq * 32;
      const int swz = (gr & 7) << 4;
      *(short8*)(x_lds + (base ^ swz)) = c0;
      *(short8*)(x_lds + ((base + 16) ^ swz)) = c1;
    }
    LGKM_BAR();   // x tile visible

    // ---- layer 1: W1 frags in regs (A), x from LDS (B) ----
    f32x4 acc[2][4];
    #pragma unroll
    for (int m = 0; m < 2; ++m)
      #pragma unroll
      for (int n = 0; n < 4; ++n) acc[m][n] = (f32x4){0.f, 0.f, 0.f, 0.f};
    #pragma unroll
    for (int ks = 0; ks < 4; ++ks) {
      const int k8 = ks * 32 + hi * 8;
      short8 b[4];
      #pragma unroll
      for (int n = 0; n < 4; ++n) {
        int row = n * 16 + lo;
        int byte = (row * 256 + k8 * 2) ^ ((row & 7) << 4);
        b[n] = *(const short8*)(x_lds + byte);
      }
      #pragma unroll
      for (int m = 0; m < 2; ++m)
        #pragma unroll
        for (int n = 0; n < 4; ++n)
          acc[m][n] = __builtin_amdgcn_mfma_f32_16x16x32_bf16(a1[ks][m], b[n], acc[m][n], 0, 0, 0);
    }

    // bias + relu -> h LDS (lane owns 4 consecutive hcols -> b64 writes)
    #pragma unroll
    for (int m = 0; m < 2; ++m) {
      const int hc = w * 32 + m * 16 + hi * 4;
      #pragma unroll
      for (int n = 0; n < 4; ++n) {
        int row = n * 16 + lo;
        ushort4 hv;
        hv.x = f2bf(fmaxf(acc[m][n][0] + bb1[m][0], 0.f));
        hv.y = f2bf(fmaxf(acc[m][n][1] + bb1[m][1], 0.f));
        hv.z = f2bf(fmaxf(acc[m][n][2] + bb1[m][2], 0.f));
        hv.w = f2bf(fmaxf(acc[m][n][3] + bb1[m][3], 0.f));
        int byte = (row * 512 + hc * 2) ^ ((row & 7) << 4);
        *(ushort4*)(h_lds + byte) = hv;
      }
    }
    LGKM_BAR();   // h visible; x_lds reads done

    // ---- layer 2: W2 frags in regs (A), h from LDS (B) ----
    f32x4 acc2[4];
    #pragma unroll
    for (int n = 0; n < 4; ++n) acc2[n] = (f32x4){0.f, 0.f, 0.f, 0.f};
    #pragma unroll
    for (int ks = 0; ks < 8; ++ks) {
      const int k8 = ks * 32 + hi * 8;
      short8 b[4];
      #pragma unroll
      for (int n = 0; n < 4; ++n) {
        int row = n * 16 + lo;
        int byte = (row * 512 + k8 * 2) ^ ((row & 7) << 4);
        b[n] = *(const short8*)(h_lds + byte);
      }
      #pragma unroll
      for (int n = 0; n < 4; ++n)
        acc2[n] = __builtin_amdgcn_mfma_f32_16x16x32_bf16(a2[ks], b[n], acc2[n], 0, 0, 0);
    }

    // rowids for the store phase (4 per thread)
    int rid[4];
    #pragma unroll
    for (int p = 0; p < 4; ++p) rid[p] = perm[g * 64 + p * 16 + (tid >> 5)];

    LGKM_BAR();   // all h reads done -> safe to overwrite h_lds with out f32

    // out f32 -> LDS (lane owns 4 consecutive ocols, swizzled rows)
    #pragma unroll
    for (int n = 0; n < 4; ++n) {
      int row = n * 16 + lo;
      const int oc = w * 16 + hi * 4;
      f32x4 o = acc2[n];
      o[0] += bb2[0]; o[1] += bb2[1]; o[2] += bb2[2]; o[3] += bb2[3];
      int byte = (row * 512 + oc * 4) ^ ((row & 7) << 4);
      *(f32x4*)(h_lds + byte) = o;
    }
    LGKM_BAR();   // out tile visible

    // row-coalesced scatter: 32 consecutive lanes write one contiguous 512B row
    #pragma unroll
    for (int p = 0; p < 4; ++p) {
      int off = p * 8192 + tid * 16;
      int row = off >> 9;
      f32x4 v = *(const f32x4*)(h_lds + (off ^ ((row & 7) << 4)));
      int colf = (off & 511) >> 2;
      float* dst = (rid[p] >= 0) ? (OUT + (size_t)rid[p] * 128 + colf) : (dump + colf);
      *(f32x4*)dst = v;
    }
    // global stores overlap next tile's gather (no vmcnt drain in LGKM_BAR)
  }
}

extern "C" void kernel_launch(void* const* d_in, const int* in_sizes, int n_in,
                              void* d_out, int out_size, void* d_ws, size_t ws_size,
                              hipStream_t stream) {
  const float* X  = (const float*)d_in[0];
  const int*   NT = (const int*)d_in[1];
  const float* W1 = (const float*)d_in[2];
  const float* B1 = (const float*)d_in[3];
  const float* W2 = (const float*)d_in[4];
  const float* B2 = (const float*)d_in[5];
  float* OUT = (float*)d_out;
  const int n = in_sizes[1];

  char* ws = (char*)d_ws;
  int* meta = (int*)ws;                                   // counts/cursors/bases
  float* dump = (float*)(ws + 512);
  int* perm = (int*)(ws + 1024);
  unsigned short* W1T = (unsigned short*)(ws + 402432);
  unsigned short* W2T = (unsigned short*)(ws + 664576);

  k_prep<<<512, 256, 0, stream>>>(W1, W2, W1T, W2T, meta);
  const int nb = (n + 255) / 256;
  k_hist<<<nb, 256, 0, stream>>>(NT, n, meta);
  k_scatter<<<nb, 256, 0, stream>>>(NT, n, meta, perm);
  k_mlpw<<<512, 512, 0, stream>>>(X, perm, meta, W1T, W2T, B1, B2, OUT, dump);
}